// Round 10
// baseline (443.911 us; speedup 1.0000x reference)
//
#include <hip/hip_runtime.h>
#include <math.h>

#define DD    64
#define TT    256
#define NROW  4096
#define BLK   512
#define GRID  256          // 256 row-tiles of 16, 1 block/CU, 8 waves = 2/SIMD

typedef __attribute__((ext_vector_type(8))) short  short8;
typedef __attribute__((ext_vector_type(4))) float  f32x4;

// Raw workgroup barrier: LDS visibility only (lgkmcnt drain), no vmcnt drain.
// Global loads/stores ride across (T4). sched_barrier(0) per rule #18.
#define BARRIER() do {                                        \
    asm volatile("s_waitcnt lgkmcnt(0)" ::: "memory");        \
    __builtin_amdgcn_sched_barrier(0);                        \
    __builtin_amdgcn_s_barrier();                             \
    __builtin_amdgcn_sched_barrier(0);                        \
  } while (0)

__device__ __forceinline__ float fexp2(float x) {
  float r;
  asm("v_exp_f32 %0, %1" : "=v"(r) : "v"(x));
  return r;
}

// packed f32->bf16 (RNE), 1 instruction for 2 values
__device__ __forceinline__ unsigned cvtpk(float lo, float hi) {
  unsigned r;
  asm("v_cvt_pk_bf16_f32 %0, %1, %2" : "=v"(r) : "v"(lo), "v"(hi));
  return r;
}
__device__ __forceinline__ unsigned short f2bf1(float f) {
  return (unsigned short)cvtpk(f, f);
}
__device__ __forceinline__ unsigned long long pack4(f32x4 v) {
  unsigned lo = cvtpk(v[0], v[1]), hi = cvtpk(v[2], v[3]);
  return (unsigned long long)lo | ((unsigned long long)hi << 32);
}
__device__ __forceinline__ short8 pack_frag(f32x4 a, f32x4 b) {
  union { unsigned u[4]; short8 s; } z;
  z.u[0] = cvtpk(a[0], a[1]); z.u[1] = cvtpk(a[2], a[3]);
  z.u[2] = cvtpk(b[0], b[1]); z.u[3] = cvtpk(b[2], b[3]);
  return z.s;
}
__device__ __forceinline__ short8 load_wfrag(const float* p) {
  f32x4 a = *(const f32x4*)p;
  f32x4 b = *(const f32x4*)(p + 4);
  return pack_frag(a, b);
}
__device__ __forceinline__ short8 load_wfrag_s(const float* p, float s) {
  f32x4 a = *(const f32x4*)p * s;
  f32x4 b = *(const f32x4*)(p + 4) * s;
  return pack_frag(a, b);
}

// A&S 7.1.26 erf, max abs err 1.5e-7
__device__ __forceinline__ float ferf(float x) {
  float ax = fabsf(x);
  float t  = __builtin_amdgcn_rcpf(fmaf(0.3275911f, ax, 1.0f));
  float p  = fmaf(1.061405429f, t, -1.453152027f);
  p = fmaf(p, t, 1.421413741f);
  p = fmaf(p, t, -0.284496736f);
  p = fmaf(p, t, 0.254829592f);
  p = p * t;
  float y = 1.0f - p * fexp2(ax * ax * -1.44269504f);
  return copysignf(y, x);
}

// bias_t[t][j] = msg_b[j] + sum_d cos(t*freq[d]+phase[d]) * msg_W[j][128+d]
__global__ void bias_kernel(const float* __restrict__ msg_W,
                            const float* __restrict__ msg_b,
                            const float* __restrict__ freq,
                            const float* __restrict__ phase,
                            float* __restrict__ bias_t) {
  __shared__ float teL[DD];
  const int t = blockIdx.x;
  const int j = threadIdx.x;
  teL[j] = cosf(fmaf((float)t, freq[j], phase[j]));
  __syncthreads();
  float acc = msg_b[j];
  const float* wrow = msg_W + j * 192 + 128;
  #pragma unroll 8
  for (int k = 0; k < DD; ++k) acc = fmaf(teL[k], wrow[k], acc);
  bias_t[t * DD + j] = acc;
}

__launch_bounds__(BLK, 1)
__global__ void scan10(const float* __restrict__ x,
                       const int*   __restrict__ mask,
                       const float* __restrict__ msg_W,
                       const float* __restrict__ W_ih,
                       const float* __restrict__ W_hh,
                       const float* __restrict__ b_ih,
                       const float* __restrict__ b_hh,
                       const float* __restrict__ bias_t,
                       float* __restrict__ out) {
  // bf16 tiles: stride 72 shorts (144 B) -> <=2-way banks on b128 frag reads
  __shared__ alignas(16) unsigned short ss[16 * 72];
  __shared__ alignas(16) unsigned short ms[16 * 72];
  __shared__ alignas(16) float s0a[16 * 68];   // fp32 state staging (G0 ph2 writes, G1 ph1 reads)
  __shared__ alignas(16) float ghl[16 * 260];  // gh transfer [rr][n*4+{r,z,n,pad}] (+mean scratch)
  __shared__ int tr_lds[TT];

  const int tid  = threadIdx.x;
  const int lane = tid & 63;
  const int wv   = tid >> 6;
  const int grp  = wv >> 2;        // 0: msg/gi/gates chain, 1: gh + out staging
  const int w4   = wv & 3;
  const int col  = lane & 15;
  const int kh   = lane >> 4;
  const int n    = w4 * 16 + col;  // output column this lane owns
  const int r16  = lane & 15;      // A-frag row
  const int row0 = blockIdx.x * 16;

  if (tid < TT) tr_lds[tid] = tid * mask[tid];

  // exp2-form gates: fold -log2e into r,z rows; +2*log2e into n rows.
  const float SC_RZ = -1.44269504f, SC_N = 2.88539008f;
  short8 wm[4], wi[3][2], wh[3][2];
  float bsum0 = 0.f, bsum1 = 0.f, bih2 = 0.f, bhh2 = 0.f;
  if (grp == 0) {
    const float* mrow = msg_W + (size_t)n * 192;
    #pragma unroll
    for (int kf = 0; kf < 4; ++kf) wm[kf] = load_wfrag(mrow + kf * 32 + kh * 8);
    const float sc[3] = {SC_RZ, SC_RZ, SC_N};
    #pragma unroll
    for (int p = 0; p < 3; ++p) {
      const float* irow = W_ih + (size_t)(p * 64 + n) * 64;
      #pragma unroll
      for (int kf = 0; kf < 2; ++kf)
        wi[p][kf] = load_wfrag_s(irow + kf * 32 + kh * 8, sc[p]);
    }
    bsum0 = (b_ih[n]      + b_hh[n])      * SC_RZ;
    bsum1 = (b_ih[64 + n] + b_hh[64 + n]) * SC_RZ;
    bih2  =  b_ih[128 + n] * SC_N;
    bhh2  =  b_hh[128 + n] * SC_N;
  } else {
    const float sc[3] = {SC_RZ, SC_RZ, SC_N};
    #pragma unroll
    for (int p = 0; p < 3; ++p) {
      const float* hrow = W_hh + (size_t)(p * 64 + n) * 64;
      #pragma unroll
      for (int kf = 0; kf < 2; ++kf)
        wh[p][kf] = load_wfrag_s(hrow + kf * 32 + kh * 8, sc[p]);
    }
  }

  // ---- s0 = mean over t (512 threads: 2 time-halves x 16 rows x 16 float4) ----
  {
    const int half = tid >> 8, rem = tid & 255;
    const int fr = rem >> 4, fd = (rem & 15) * 4;
    const float* px = x + ((size_t)half * 128) * (NROW * DD)
                        + (size_t)(row0 + fr) * DD + fd;
    f32x4 acc = {0.f, 0.f, 0.f, 0.f};
    #pragma unroll 4
    for (int tl = 0; tl < 128; ++tl) {
      f32x4 v = *(const f32x4*)(px + (size_t)tl * (NROW * DD));
      acc += v;
    }
    float* dst = (half == 0) ? &s0a[fr * 68 + fd] : &ghl[rem * 4];
    *(f32x4*)dst = acc;
  }
  __syncthreads();
  if (tid < 256) {
    const int fr = tid >> 4, fd = (tid & 15) * 4;
    f32x4 a = *(const f32x4*)&s0a[fr * 68 + fd];
    f32x4 b = *(const f32x4*)&ghl[tid * 4];
    f32x4 m = (a + b) * (1.0f / 256.0f);
    *(f32x4*)&s0a[fr * 68 + fd] = m;
    *(unsigned long long*)&ss[fr * 72 + fd] = pack4(m);
  }
  __syncthreads();

  // G0: fp32 state regs, first bias, x A-frag register pipeline (2-deep)
  float s_reg[4] = {0.f, 0.f, 0.f, 0.f};
  float btc = 0.f;
  f32x4 xA0 = {0,0,0,0}, xA1 = {0,0,0,0}, xA2 = {0,0,0,0}, xA3 = {0,0,0,0};
  f32x4 xB0 = {0,0,0,0}, xB1 = {0,0,0,0}, xB2 = {0,0,0,0}, xB3 = {0,0,0,0};
  if (grp == 0) {
    #pragma unroll
    for (int i = 0; i < 4; ++i) s_reg[i] = s0a[(kh * 4 + i) * 68 + n];
    btc = bias_t[n];                 // tr[0] = 0
    // x(t=0) frags (tr[0]=0) and x(t=1)
    const float* p0 = x + (size_t)(row0 + r16) * DD + kh * 8;
    xA0 = *(const f32x4*)p0;       xA1 = *(const f32x4*)(p0 + 4);
    xA2 = *(const f32x4*)(p0 + 32); xA3 = *(const f32x4*)(p0 + 36);
    const float* p1 = x + ((size_t)tr_lds[1] * NROW + row0 + r16) * DD + kh * 8;
    xB0 = *(const f32x4*)p1;       xB1 = *(const f32x4*)(p1 + 4);
    xB2 = *(const f32x4*)(p1 + 32); xB3 = *(const f32x4*)(p1 + 36);
    __builtin_amdgcn_s_setprio(1);   // critical-chain waves get priority
  }

  // G1 out-staging map: 256 threads cover 16 rows x 16 float4
  const int t1  = tid & 255;
  const int fr1 = t1 >> 4;
  const int fd1 = (t1 & 15) * 4;

  auto body = [&](int t, f32x4& v0, f32x4& v1, f32x4& v2, f32x4& v3) {
    // ================= PHASE 1 =================
    if (grp == 0) {
      // amx: register-fed x-part (off-path; independent of s(t-1))
      short8 xa0 = pack_frag(v0, v1);
      short8 xa1 = pack_frag(v2, v3);
      f32x4 amx = {0.f,0.f,0.f,0.f};
      amx = __builtin_amdgcn_mfma_f32_16x16x32_bf16(xa0, wm[0], amx, 0, 0, 0);
      amx = __builtin_amdgcn_mfma_f32_16x16x32_bf16(xa1, wm[1], amx, 0, 0, 0);
      // reload this reg set with x(tr[t+2]) (fire-and-forget, 2-step cover)
      if (t + 2 < TT) {
        const float* pn = x + ((size_t)tr_lds[t + 2] * NROW + row0 + r16) * DD + kh * 8;
        v0 = *(const f32x4*)pn;        v1 = *(const f32x4*)(pn + 4);
        v2 = *(const f32x4*)(pn + 32); v3 = *(const f32x4*)(pn + 36);
      }
      float btn = 0.f;
      if (t + 1 < TT) btn = bias_t[tr_lds[t + 1] * DD + n];  // 1-step-ahead (L2)
      // s-part MFMA from ss
      const unsigned short* as = &ss[r16 * 72];
      short8 sa0 = *(const short8*)(as + kh * 8);
      short8 sa1 = *(const short8*)(as + 32 + kh * 8);
      f32x4 ams = {0.f,0.f,0.f,0.f};
      ams = __builtin_amdgcn_mfma_f32_16x16x32_bf16(sa0, wm[2], ams, 0, 0, 0);
      ams = __builtin_amdgcn_mfma_f32_16x16x32_bf16(sa1, wm[3], ams, 0, 0, 0);
      // GELU -> ms
      #pragma unroll
      for (int i = 0; i < 4; ++i) {
        float a = amx[i] + ams[i] + btc;
        float g = 0.5f * a * (1.0f + ferf(a * 0.70710678118654752f));
        ms[(kh * 4 + i) * 72 + n] = f2bf1(g);
      }
      btc = btn;
    } else {
      // gh = s @ W_hh^T (scaled)
      const unsigned short* as = &ss[r16 * 72];
      short8 sa0 = *(const short8*)(as + kh * 8);
      short8 sa1 = *(const short8*)(as + 32 + kh * 8);
      f32x4 agh[3];
      #pragma unroll
      for (int p = 0; p < 3; ++p) {
        f32x4 c = {0.f,0.f,0.f,0.f};
        c = __builtin_amdgcn_mfma_f32_16x16x32_bf16(sa0, wh[p][0], c, 0, 0, 0);
        c = __builtin_amdgcn_mfma_f32_16x16x32_bf16(sa1, wh[p][1], c, 0, 0, 0);
        agh[p] = c;
      }
      #pragma unroll
      for (int i = 0; i < 4; ++i) {
        f32x4 gv = { agh[0][i], agh[1][i], agh[2][i], 0.f };
        *(f32x4*)&ghl[(kh * 4 + i) * 260 + n * 4] = gv;
      }
      // out-write of t-1 from s0a (written ph2(t-1); G0 rewrites only in ph2(t))
      if (t > 0) {
        f32x4 ov = *(const f32x4*)&s0a[fr1 * 68 + fd1];
        *(f32x4*)(out + ((size_t)(t - 1) * NROW + row0 + fr1) * DD + fd1) = ov;
      }
    }
    BARRIER();  // B1: ms & ghl visible; ss/s0a reads of phase 1 done

    // ================= PHASE 2 =================
    if (grp == 0) {
      // hoisted ghl reads (latency hides under gi MFMAs)
      f32x4 gh4[4];
      #pragma unroll
      for (int i = 0; i < 4; ++i)
        gh4[i] = *(const f32x4*)&ghl[(kh * 4 + i) * 260 + n * 4];
      const unsigned short* am = &ms[r16 * 72];
      short8 ma0 = *(const short8*)(am + kh * 8);
      short8 ma1 = *(const short8*)(am + 32 + kh * 8);
      f32x4 agi[3];
      #pragma unroll
      for (int p = 0; p < 3; ++p) {
        f32x4 c = {0.f,0.f,0.f,0.f};
        c = __builtin_amdgcn_mfma_f32_16x16x32_bf16(ma0, wi[p][0], c, 0, 0, 0);
        c = __builtin_amdgcn_mfma_f32_16x16x32_bf16(ma1, wi[p][1], c, 0, 0, 0);
        agi[p] = c;
      }
      // gates (exp2-folded): rg = 1/(1+2^er), ng = 1 - 2/(1+2^yn)
      #pragma unroll
      for (int i = 0; i < 4; ++i) {
        const int rr = kh * 4 + i;
        float er = agi[0][i] + gh4[i][0] + bsum0;
        float ez = agi[1][i] + gh4[i][1] + bsum1;
        float rg = __builtin_amdgcn_rcpf(1.0f + fexp2(er));
        float zg = __builtin_amdgcn_rcpf(1.0f + fexp2(ez));
        float yn = fmaf(rg, gh4[i][2] + bhh2, agi[2][i] + bih2);
        float ng = 1.0f - 2.0f * __builtin_amdgcn_rcpf(1.0f + fexp2(yn));
        float sn = fmaf(zg, s_reg[i] - ng, ng);
        s_reg[i] = sn;
        ss[rr * 72 + n]  = f2bf1(sn);
        s0a[rr * 68 + n] = sn;
      }
    }
    // G1: nothing in phase 2
    BARRIER();  // B2: ss/s0a updated for next step
  };

  // statically role-swapped 2x unroll (rule #20: no dynamic reg indexing)
  for (int tt = 0; tt < TT; tt += 2) {
    body(tt,     xA0, xA1, xA2, xA3);
    body(tt + 1, xB0, xB1, xB2, xB3);
  }

  // final output row (t = 255); s0a drained at last B2
  if (grp == 1) {
    f32x4 ov = *(const f32x4*)&s0a[fr1 * 68 + fd1];
    *(f32x4*)(out + ((size_t)(TT - 1) * NROW + row0 + fr1) * DD + fd1) = ov;
  }
}

extern "C" void kernel_launch(void* const* d_in, const int* in_sizes, int n_in,
                              void* d_out, int out_size, void* d_ws, size_t ws_size,
                              hipStream_t stream) {
  const float* x      = (const float*)d_in[0];
  const int*   mask   = (const int*)  d_in[1];
  const float* msg_W  = (const float*)d_in[2];
  const float* msg_b  = (const float*)d_in[3];
  const float* W_ih   = (const float*)d_in[4];
  const float* W_hh   = (const float*)d_in[5];
  const float* b_ih   = (const float*)d_in[6];
  const float* b_hh   = (const float*)d_in[7];
  const float* freq   = (const float*)d_in[8];
  const float* phase  = (const float*)d_in[9];
  float* out    = (float*)d_out;
  float* bias_t = (float*)d_ws;   // TT*DD floats = 64 KB

  (void)in_sizes; (void)n_in; (void)out_size; (void)ws_size;

  bias_kernel<<<TT, DD, 0, stream>>>(msg_W, msg_b, freq, phase, bias_t);
  scan10<<<GRID, BLK, 0, stream>>>(x, mask, msg_W, W_ih, W_hh,
                                   b_ih, b_hh, bias_t, out);
}

// Round 11
// 311.123 us; speedup vs baseline: 1.4268x; 1.4268x over previous
//
#include <hip/hip_runtime.h>
#include <math.h>

#define DD    64
#define TT    256
#define NROW  4096
#define BLK   512
#define GRID  256          // 256 row-tiles of 16, 1 block/CU, 8 waves = 2/SIMD

typedef __attribute__((ext_vector_type(8))) short  short8;
typedef __attribute__((ext_vector_type(4))) float  f32x4;

// Raw workgroup barrier: LDS visibility only (lgkmcnt drain), no vmcnt drain.
// Global loads/stores ride across (T4). sched_barrier(0) per rule #18.
#define BARRIER() do {                                        \
    asm volatile("s_waitcnt lgkmcnt(0)" ::: "memory");        \
    __builtin_amdgcn_sched_barrier(0);                        \
    __builtin_amdgcn_s_barrier();                             \
    __builtin_amdgcn_sched_barrier(0);                        \
  } while (0)

__device__ __forceinline__ float fexp2(float x) {
  float r;
  asm("v_exp_f32 %0, %1" : "=v"(r) : "v"(x));
  return r;
}

// packed f32->bf16 (RNE), 1 instruction for 2 values
__device__ __forceinline__ unsigned cvtpk(float lo, float hi) {
  unsigned r;
  asm("v_cvt_pk_bf16_f32 %0, %1, %2" : "=v"(r) : "v"(lo), "v"(hi));
  return r;
}
__device__ __forceinline__ unsigned short f2bf1(float f) {
  return (unsigned short)cvtpk(f, f);
}
__device__ __forceinline__ unsigned long long pack4(f32x4 v) {
  unsigned lo = cvtpk(v[0], v[1]), hi = cvtpk(v[2], v[3]);
  return (unsigned long long)lo | ((unsigned long long)hi << 32);
}
__device__ __forceinline__ short8 pack_frag(f32x4 a, f32x4 b) {
  union { unsigned u[4]; short8 s; } z;
  z.u[0] = cvtpk(a[0], a[1]); z.u[1] = cvtpk(a[2], a[3]);
  z.u[2] = cvtpk(b[0], b[1]); z.u[3] = cvtpk(b[2], b[3]);
  return z.s;
}
__device__ __forceinline__ short8 load_wfrag(const float* p) {
  f32x4 a = *(const f32x4*)p;
  f32x4 b = *(const f32x4*)(p + 4);
  return pack_frag(a, b);
}
__device__ __forceinline__ short8 load_wfrag_s(const float* p, float s) {
  f32x4 a = *(const f32x4*)p * s;
  f32x4 b = *(const f32x4*)(p + 4) * s;
  return pack_frag(a, b);
}

// A&S 7.1.26 erf, max abs err 1.5e-7
__device__ __forceinline__ float ferf(float x) {
  float ax = fabsf(x);
  float t  = __builtin_amdgcn_rcpf(fmaf(0.3275911f, ax, 1.0f));
  float p  = fmaf(1.061405429f, t, -1.453152027f);
  p = fmaf(p, t, 1.421413741f);
  p = fmaf(p, t, -0.284496736f);
  p = fmaf(p, t, 0.254829592f);
  p = p * t;
  float y = 1.0f - p * fexp2(ax * ax * -1.44269504f);
  return copysignf(y, x);
}

// bias_t[t][j] = msg_b[j] + sum_d cos(t*freq[d]+phase[d]) * msg_W[j][128+d]
__global__ void bias_kernel(const float* __restrict__ msg_W,
                            const float* __restrict__ msg_b,
                            const float* __restrict__ freq,
                            const float* __restrict__ phase,
                            float* __restrict__ bias_t) {
  __shared__ float teL[DD];
  const int t = blockIdx.x;
  const int j = threadIdx.x;
  teL[j] = cosf(fmaf((float)t, freq[j], phase[j]));
  __syncthreads();
  float acc = msg_b[j];
  const float* wrow = msg_W + j * 192 + 128;
  #pragma unroll 8
  for (int k = 0; k < DD; ++k) acc = fmaf(teL[k], wrow[k], acc);
  bias_t[t * DD + j] = acc;
}

__launch_bounds__(BLK, 1)
__global__ void scan11(const float* __restrict__ x,
                       const int*   __restrict__ mask,
                       const float* __restrict__ msg_W,
                       const float* __restrict__ W_ih,
                       const float* __restrict__ W_hh,
                       const float* __restrict__ b_ih,
                       const float* __restrict__ b_hh,
                       const float* __restrict__ bias_t,
                       float* __restrict__ out) {
  // bf16 tiles: stride 72 shorts (144 B) -> <=2-way banks on b128 frag reads
  __shared__ alignas(16) unsigned short xs[16 * 72];
  __shared__ alignas(16) unsigned short ss[16 * 72];
  __shared__ alignas(16) unsigned short ms[16 * 72];
  __shared__ alignas(16) float s0a[16 * 68];   // fp32 state staging (G0 ph2 writes, G1 ph1 reads)
  __shared__ alignas(16) float ghl[16 * 260];  // gh transfer [rr][n*4+{r,z,n,pad}] (+mean scratch)
  __shared__ int tr_lds[TT];

  const int tid  = threadIdx.x;
  const int lane = tid & 63;
  const int wv   = tid >> 6;
  const int grp  = wv >> 2;        // 0: msg/gi/gates chain, 1: gh + staging
  const int w4   = wv & 3;
  const int col  = lane & 15;
  const int kh   = lane >> 4;
  const int n    = w4 * 16 + col;  // output column this lane owns
  const int r16  = lane & 15;
  const int row0 = blockIdx.x * 16;

  if (tid < TT) tr_lds[tid] = tid * mask[tid];

  // exp2-form gates: fold -log2e into r,z rows; +2*log2e into n rows.
  const float SC_RZ = -1.44269504f, SC_N = 2.88539008f;
  short8 wm[4], wi[3][2], wh[3][2];
  float bsum0 = 0.f, bsum1 = 0.f, bih2 = 0.f, bhh2 = 0.f;
  if (grp == 0) {
    const float* mrow = msg_W + (size_t)n * 192;
    #pragma unroll
    for (int kf = 0; kf < 4; ++kf) wm[kf] = load_wfrag(mrow + kf * 32 + kh * 8);
    const float sc[3] = {SC_RZ, SC_RZ, SC_N};
    #pragma unroll
    for (int p = 0; p < 3; ++p) {
      const float* irow = W_ih + (size_t)(p * 64 + n) * 64;
      #pragma unroll
      for (int kf = 0; kf < 2; ++kf)
        wi[p][kf] = load_wfrag_s(irow + kf * 32 + kh * 8, sc[p]);
    }
    bsum0 = (b_ih[n]      + b_hh[n])      * SC_RZ;
    bsum1 = (b_ih[64 + n] + b_hh[64 + n]) * SC_RZ;
    bih2  =  b_ih[128 + n] * SC_N;
    bhh2  =  b_hh[128 + n] * SC_N;
  } else {
    const float sc[3] = {SC_RZ, SC_RZ, SC_N};
    #pragma unroll
    for (int p = 0; p < 3; ++p) {
      const float* hrow = W_hh + (size_t)(p * 64 + n) * 64;
      #pragma unroll
      for (int kf = 0; kf < 2; ++kf)
        wh[p][kf] = load_wfrag_s(hrow + kf * 32 + kh * 8, sc[p]);
    }
  }

  // ---- s0 = mean over t (512 threads: 2 time-halves x 16 rows x 16 float4) ----
  {
    const int half = tid >> 8, rem = tid & 255;
    const int fr = rem >> 4, fd = (rem & 15) * 4;
    const float* px = x + ((size_t)half * 128) * (NROW * DD)
                        + (size_t)(row0 + fr) * DD + fd;
    f32x4 acc = {0.f, 0.f, 0.f, 0.f};
    #pragma unroll 4
    for (int tl = 0; tl < 128; ++tl) {
      f32x4 v = *(const f32x4*)(px + (size_t)tl * (NROW * DD));
      acc += v;
    }
    float* dst = (half == 0) ? &s0a[fr * 68 + fd] : &ghl[rem * 4];
    *(f32x4*)dst = acc;
  }
  __syncthreads();
  if (tid < 256) {
    const int fr = tid >> 4, fd = (tid & 15) * 4;
    f32x4 a = *(const f32x4*)&s0a[fr * 68 + fd];
    f32x4 b = *(const f32x4*)&ghl[tid * 4];
    f32x4 m = (a + b) * (1.0f / 256.0f);
    *(f32x4*)&s0a[fr * 68 + fd] = m;
    *(unsigned long long*)&ss[fr * 72 + fd] = pack4(m);
    f32x4 xv0 = *(const f32x4*)(x + (size_t)(row0 + fr) * DD + fd);  // tr[0]=0
    *(unsigned long long*)&xs[fr * 72 + fd] = pack4(xv0);
  }
  __syncthreads();

  // G0: fp32 state registers + bias for t=0
  float s_reg[4] = {0.f, 0.f, 0.f, 0.f};
  float btc = 0.f;
  if (grp == 0) {
    #pragma unroll
    for (int i = 0; i < 4; ++i) s_reg[i] = s0a[(kh * 4 + i) * 68 + n];
    btc = bias_t[n];                 // tr[0] = 0
    __builtin_amdgcn_s_setprio(1);   // critical-chain waves get priority
  }

  // G1 staging map: 256 threads cover 16 rows x 16 float4
  const int t1  = tid & 255;
  const int fr1 = t1 >> 4;
  const int fd1 = (t1 & 15) * 4;

  // 2-deep x pipeline: xvA/xvB hold x(tr[t+1]), x(tr[t+2]) as f32x4/thread.
  f32x4 xvA = {0.f,0.f,0.f,0.f}, xvB = {0.f,0.f,0.f,0.f};
  if (grp == 1)
    xvA = *(const f32x4*)(x + ((size_t)tr_lds[1] * NROW + row0 + fr1) * DD + fd1);

  auto body = [&](int t, f32x4& xv_use, f32x4& xv_load) {
    // ================= PHASE 1 =================
    if (grp == 0) {
      const unsigned short* ax = &xs[r16 * 72];
      const unsigned short* as = &ss[r16 * 72];
      short8 xa0 = *(const short8*)(ax + kh * 8);
      short8 xa1 = *(const short8*)(ax + 32 + kh * 8);
      short8 sa0 = *(const short8*)(as + kh * 8);
      short8 sa1 = *(const short8*)(as + 32 + kh * 8);
      float btn = 0.f;
      if (t + 1 < TT) btn = bias_t[tr_lds[t + 1] * DD + n];  // 1-step-ahead (L2)
      f32x4 amx = {0.f,0.f,0.f,0.f};
      amx = __builtin_amdgcn_mfma_f32_16x16x32_bf16(xa0, wm[0], amx, 0, 0, 0);
      amx = __builtin_amdgcn_mfma_f32_16x16x32_bf16(xa1, wm[1], amx, 0, 0, 0);
      f32x4 ams = {0.f,0.f,0.f,0.f};
      ams = __builtin_amdgcn_mfma_f32_16x16x32_bf16(sa0, wm[2], ams, 0, 0, 0);
      ams = __builtin_amdgcn_mfma_f32_16x16x32_bf16(sa1, wm[3], ams, 0, 0, 0);
      #pragma unroll
      for (int i = 0; i < 4; ++i) {
        float a = amx[i] + ams[i] + btc;
        float g = 0.5f * a * (1.0f + ferf(a * 0.70710678118654752f));
        ms[(kh * 4 + i) * 72 + n] = f2bf1(g);
      }
      btc = btn;
    } else {
      // gh = s @ W_hh^T (scaled)
      const unsigned short* as = &ss[r16 * 72];
      short8 sa0 = *(const short8*)(as + kh * 8);
      short8 sa1 = *(const short8*)(as + 32 + kh * 8);
      f32x4 agh[3];
      #pragma unroll
      for (int p = 0; p < 3; ++p) {
        f32x4 c = {0.f,0.f,0.f,0.f};
        c = __builtin_amdgcn_mfma_f32_16x16x32_bf16(sa0, wh[p][0], c, 0, 0, 0);
        c = __builtin_amdgcn_mfma_f32_16x16x32_bf16(sa1, wh[p][1], c, 0, 0, 0);
        agh[p] = c;
      }
      #pragma unroll
      for (int i = 0; i < 4; ++i) {
        f32x4 gv = { agh[0][i], agh[1][i], agh[2][i], 0.f };
        *(f32x4*)&ghl[(kh * 4 + i) * 260 + n * 4] = gv;
      }
      // out-write of t-1 from s0a (ds_read drains at B1, before G0 rewrites)
      if (t > 0) {
        f32x4 ov = *(const f32x4*)&s0a[fr1 * 68 + fd1];
        *(f32x4*)(out + ((size_t)(t - 1) * NROW + row0 + fr1) * DD + fd1) = ov;
      }
      // issue x(tr[t+2]) load; consumed in ph2 of t+1 (~1.3 steps of cover)
      if (t + 2 < TT)
        xv_load = *(const f32x4*)(x + ((size_t)tr_lds[t + 2] * NROW + row0 + fr1) * DD + fd1);
    }
    BARRIER();  // B1: ms & ghl visible; xs/ss/s0a reads of phase 1 done

    // ================= PHASE 2 =================
    if (grp == 0) {
      f32x4 gh4[4];
      #pragma unroll
      for (int i = 0; i < 4; ++i)
        gh4[i] = *(const f32x4*)&ghl[(kh * 4 + i) * 260 + n * 4];
      const unsigned short* am = &ms[r16 * 72];
      short8 ma0 = *(const short8*)(am + kh * 8);
      short8 ma1 = *(const short8*)(am + 32 + kh * 8);
      f32x4 agi[3];
      #pragma unroll
      for (int p = 0; p < 3; ++p) {
        f32x4 c = {0.f,0.f,0.f,0.f};
        c = __builtin_amdgcn_mfma_f32_16x16x32_bf16(ma0, wi[p][0], c, 0, 0, 0);
        c = __builtin_amdgcn_mfma_f32_16x16x32_bf16(ma1, wi[p][1], c, 0, 0, 0);
        agi[p] = c;
      }
      // gates (exp2-folded): rg = 1/(1+2^er), ng = 1 - 2/(1+2^yn)
      #pragma unroll
      for (int i = 0; i < 4; ++i) {
        const int rr = kh * 4 + i;
        float er = agi[0][i] + gh4[i][0] + bsum0;
        float ez = agi[1][i] + gh4[i][1] + bsum1;
        float rg = __builtin_amdgcn_rcpf(1.0f + fexp2(er));
        float zg = __builtin_amdgcn_rcpf(1.0f + fexp2(ez));
        float yn = fmaf(rg, gh4[i][2] + bhh2, agi[2][i] + bih2);
        float ng = 1.0f - 2.0f * __builtin_amdgcn_rcpf(1.0f + fexp2(yn));
        float sn = fmaf(zg, s_reg[i] - ng, ng);
        s_reg[i] = sn;
        ss[rr * 72 + n]  = f2bf1(sn);
        s0a[rr * 68 + n] = sn;
      }
    } else {
      // stage xs(t+1) from xv_use (loaded in ph1 of t-1; long since arrived)
      if (t + 1 < TT)
        *(unsigned long long*)&xs[fr1 * 72 + fd1] = pack4(xv_use);
    }
    BARRIER();  // B2: ss/s0a/xs updated for next step
  };

  // statically role-swapped 2x unroll (rule #20: no dynamic reg indexing)
  for (int tt = 0; tt < TT; tt += 2) {
    body(tt,     xvA, xvB);
    body(tt + 1, xvB, xvA);
  }

  // final output row (t = 255); s0a drained at last B2
  if (grp == 1) {
    f32x4 ov = *(const f32x4*)&s0a[fr1 * 68 + fd1];
    *(f32x4*)(out + ((size_t)(TT - 1) * NROW + row0 + fr1) * DD + fd1) = ov;
  }
}

extern "C" void kernel_launch(void* const* d_in, const int* in_sizes, int n_in,
                              void* d_out, int out_size, void* d_ws, size_t ws_size,
                              hipStream_t stream) {
  const float* x      = (const float*)d_in[0];
  const int*   mask   = (const int*)  d_in[1];
  const float* msg_W  = (const float*)d_in[2];
  const float* msg_b  = (const float*)d_in[3];
  const float* W_ih   = (const float*)d_in[4];
  const float* W_hh   = (const float*)d_in[5];
  const float* b_ih   = (const float*)d_in[6];
  const float* b_hh   = (const float*)d_in[7];
  const float* freq   = (const float*)d_in[8];
  const float* phase  = (const float*)d_in[9];
  float* out    = (float*)d_out;
  float* bias_t = (float*)d_ws;   // TT*DD floats = 64 KB

  (void)in_sizes; (void)n_in; (void)out_size; (void)ws_size;

  bias_kernel<<<TT, DD, 0, stream>>>(msg_W, msg_b, freq, phase, bias_t);
  scan11<<<GRID, BLK, 0, stream>>>(x, mask, msg_W, W_ih, W_hh,
                                   b_ih, b_hh, bias_t, out);
}